// Round 2
// baseline (3917.913 us; speedup 1.0000x reference)
//
#include <hip/hip_runtime.h>
#include <hip/hip_bf16.h>

#define N_NODES   100000
#define N_FEAT    512
#define HIDDEN    64
#define N_CLASSES 40
#define KITER     10
#define ALPHA     0.1f

__device__ __forceinline__ float bf2f(unsigned short u) {
    union { unsigned int i; float f; } c;
    c.i = ((unsigned int)u) << 16;
    return c.f;
}

// ---------------- dtype detection (runs every call; data-driven, deterministic) ----
__global__ void zero_flags_kernel(int* __restrict__ flags) {
    if (threadIdx.x < 2) flags[threadIdx.x] = 0;
}

// flags[0] > 0  <=>  float tensors are fp32 (NaN/Inf bf16 bit-patterns found in W1 raw halves)
__global__ void detect_float_kernel(const unsigned short* __restrict__ w1raw,
                                    int* __restrict__ flags) {
    int i = blockIdx.x * blockDim.x + threadIdx.x;   // first 32768 uint16 slots = 64KiB
    if (i < 32768) {
        unsigned short u = w1raw[i];
        if ((u & 0x7F80u) == 0x7F80u) atomicAdd(&flags[0], 1);
    }
}

// flags[1] > 0  <=>  edges are int32 (some odd 32-bit word among first 2048 pairs nonzero)
__global__ void detect_edge_kernel(const int* __restrict__ ei, int* __restrict__ flags) {
    int i = blockIdx.x * blockDim.x + threadIdx.x;   // 2048 odd words
    if (i < 2048) {
        if (ei[2 * i + 1] != 0) atomicAdd(&flags[1], 1);
    }
}

__device__ __forceinline__ int edge_row(const int* ei, int e, int E, int i64f) {
    return i64f ? ei[2 * e] : ei[e];
}
__device__ __forceinline__ int edge_col(const int* ei, int e, int E, int i64f) {
    return i64f ? ei[2 * E + 2 * e] : ei[E + e];
}

// ---------------- MLP: h0 = relu(x@W1+b1)@W2+b2, fp32 out ----------------
// one wave per node, 4 waves per block; dual dtype path on flags[0]
__global__ __launch_bounds__(256) void mlp_kernel(
    const void* __restrict__ xp,
    const void* __restrict__ W1p,
    const void* __restrict__ b1p,
    const void* __restrict__ W2p,
    const void* __restrict__ b2p,
    const int* __restrict__ flags,
    float* __restrict__ h0)
{
    __shared__ float xs[4][N_FEAT];
    __shared__ float hs[4][HIDDEN];
    const int wave = threadIdx.x >> 6;
    const int lane = threadIdx.x & 63;
    const int node = blockIdx.x * 4 + wave;
    const int isf32 = flags[0] > 0;

    if (isf32) {
        const float4* xr = (const float4*)((const float*)xp + (size_t)node * N_FEAT);
        float4 a = xr[lane];
        float4 b = xr[lane + 64];
        int p = lane * 4;
        xs[wave][p + 0] = a.x; xs[wave][p + 1] = a.y;
        xs[wave][p + 2] = a.z; xs[wave][p + 3] = a.w;
        xs[wave][256 + p + 0] = b.x; xs[wave][256 + p + 1] = b.y;
        xs[wave][256 + p + 2] = b.z; xs[wave][256 + p + 3] = b.w;
    } else {
        const uint4* xr = (const uint4*)((const unsigned short*)xp + (size_t)node * N_FEAT);
        uint4 p = xr[lane];
        int b = lane * 8;
        xs[wave][b + 0] = bf2f((unsigned short)(p.x & 0xffff));
        xs[wave][b + 1] = bf2f((unsigned short)(p.x >> 16));
        xs[wave][b + 2] = bf2f((unsigned short)(p.y & 0xffff));
        xs[wave][b + 3] = bf2f((unsigned short)(p.y >> 16));
        xs[wave][b + 4] = bf2f((unsigned short)(p.z & 0xffff));
        xs[wave][b + 5] = bf2f((unsigned short)(p.z >> 16));
        xs[wave][b + 6] = bf2f((unsigned short)(p.w & 0xffff));
        xs[wave][b + 7] = bf2f((unsigned short)(p.w >> 16));
    }
    __syncthreads();

    // layer 1: lane computes hidden unit `lane`
    float acc;
    if (isf32) {
        const float* W1 = (const float*)W1p;
        acc = ((const float*)b1p)[lane];
        #pragma unroll 8
        for (int k = 0; k < N_FEAT; ++k)
            acc = fmaf(xs[wave][k], W1[k * HIDDEN + lane], acc);
    } else {
        const unsigned short* W1 = (const unsigned short*)W1p;
        acc = bf2f(((const unsigned short*)b1p)[lane]);
        #pragma unroll 8
        for (int k = 0; k < N_FEAT; ++k)
            acc = fmaf(xs[wave][k], bf2f(W1[k * HIDDEN + lane]), acc);
    }
    hs[wave][lane] = fmaxf(acc, 0.0f);
    __syncthreads();

    // layer 2: lanes 0..39 compute class outputs
    if (lane < N_CLASSES) {
        float a2;
        if (isf32) {
            const float* W2 = (const float*)W2p;
            a2 = ((const float*)b2p)[lane];
            #pragma unroll
            for (int j = 0; j < HIDDEN; ++j)
                a2 = fmaf(hs[wave][j], W2[j * N_CLASSES + lane], a2);
        } else {
            const unsigned short* W2 = (const unsigned short*)W2p;
            a2 = bf2f(((const unsigned short*)b2p)[lane]);
            #pragma unroll
            for (int j = 0; j < HIDDEN; ++j)
                a2 = fmaf(hs[wave][j], bf2f(W2[j * N_CLASSES + lane]), a2);
        }
        h0[(size_t)node * N_CLASSES + lane] = a2;
    }
}

// ---------------- graph preprocessing ----------------
__global__ void zero_cnt_kernel(int* __restrict__ cnt) {
    int i = blockIdx.x * blockDim.x + threadIdx.x;
    if (i < N_NODES) cnt[i] = 0;
}

__global__ void count_kernel(const int* __restrict__ ei, const int* __restrict__ flags,
                             int* __restrict__ cnt, int E) {
    int e = blockIdx.x * blockDim.x + threadIdx.x;
    int i64f = flags[1] == 0;
    if (e < E) atomicAdd(&cnt[edge_col(ei, e, E, i64f)], 1);
}

__global__ void dinv_kernel(const int* __restrict__ cnt, float* __restrict__ dinv) {
    int i = blockIdx.x * blockDim.x + threadIdx.x;
    if (i < N_NODES) dinv[i] = rsqrtf((float)cnt[i] + 1.0f);  // +1 self-loop
}

// single-block exclusive scan of cnt -> rptr (and wpos copy), tiles of 1024
__global__ __launch_bounds__(1024) void scan_kernel(
    const int* __restrict__ cnt, int* __restrict__ rptr, int* __restrict__ wpos, int E)
{
    __shared__ int buf[1024];
    __shared__ int carry_s;
    const int t = threadIdx.x;
    if (t == 0) carry_s = 0;
    __syncthreads();
    for (int base = 0; base < N_NODES; base += 1024) {
        int i = base + t;
        int v = (i < N_NODES) ? cnt[i] : 0;
        buf[t] = v;
        __syncthreads();
        for (int off = 1; off < 1024; off <<= 1) {
            int add = (t >= off) ? buf[t - off] : 0;
            __syncthreads();
            buf[t] += add;
            __syncthreads();
        }
        int incl = buf[t];
        int excl = incl - v;
        int carry = carry_s;
        if (i < N_NODES) { rptr[i] = carry + excl; wpos[i] = carry + excl; }
        __syncthreads();
        if (t == 1023) carry_s = carry + incl;
        __syncthreads();
    }
    if (t == 0) rptr[N_NODES] = E;
}

__global__ void fill_kernel(const int* __restrict__ ei, const int* __restrict__ flags,
                            const float* __restrict__ dinv, int* __restrict__ wpos,
                            int* __restrict__ srow, float* __restrict__ snorm, int E)
{
    int e = blockIdx.x * blockDim.x + threadIdx.x;
    int i64f = flags[1] == 0;
    if (e < E) {
        int r = edge_row(ei, e, E, i64f);
        int c = edge_col(ei, e, E, i64f);
        int pos = atomicAdd(&wpos[c], 1);
        srow[pos]  = r;
        snorm[pos] = dinv[r] * dinv[c];
    }
}

// ---------------- propagation: z_out = a*h0 + (1-a)*(A_hat @ z) ----------------
// pull mode via CSR-by-destination; one wave per node, lanes 0..39 = features
__global__ __launch_bounds__(256) void prop_kernel(
    const float* __restrict__ z, const float* __restrict__ h0,
    const float* __restrict__ dinv, const int* __restrict__ rptr,
    const int* __restrict__ srow, const float* __restrict__ snorm,
    float* __restrict__ zout)
{
    const int wave = threadIdx.x >> 6;
    const int lane = threadIdx.x & 63;
    const int node = blockIdx.x * 4 + wave;
    if (lane >= N_CLASSES) return;

    const int beg = rptr[node], end = rptr[node + 1];
    float acc = 0.0f;
    for (int j = beg; j < end; ++j) {
        int r   = srow[j];
        float w = snorm[j];
        acc = fmaf(w, z[(size_t)r * N_CLASSES + lane], acc);
    }
    float di   = dinv[node];
    float self = di * di * z[(size_t)node * N_CLASSES + lane];
    float out  = ALPHA * h0[(size_t)node * N_CLASSES + lane]
               + (1.0f - ALPHA) * (acc + self);
    zout[(size_t)node * N_CLASSES + lane] = out;
}

// ---------------- log_softmax + store (fp32 or bf16 per flags[0]) ----------------
__global__ __launch_bounds__(256) void lsm_kernel(
    const float* __restrict__ z, const int* __restrict__ flags, void* __restrict__ outp)
{
    const int wave = threadIdx.x >> 6;
    const int lane = threadIdx.x & 63;
    const int node = blockIdx.x * 4 + wave;
    const int isf32 = flags[0] > 0;

    float v = (lane < N_CLASSES) ? z[(size_t)node * N_CLASSES + lane] : -1e30f;
    float m = v;
    #pragma unroll
    for (int o = 32; o; o >>= 1) m = fmaxf(m, __shfl_xor(m, o, 64));
    float e = (lane < N_CLASSES) ? expf(v - m) : 0.0f;
    float s = e;
    #pragma unroll
    for (int o = 32; o; o >>= 1) s += __shfl_xor(s, o, 64);
    float ls = logf(s);
    if (lane < N_CLASSES) {
        float r = v - m - ls;
        size_t idx = (size_t)node * N_CLASSES + lane;
        if (isf32) ((float*)outp)[idx] = r;
        else       ((__hip_bfloat16*)outp)[idx] = __float2bfloat16(r);
    }
}

extern "C" void kernel_launch(void* const* d_in, const int* in_sizes, int n_in,
                              void* d_out, int out_size, void* d_ws, size_t ws_size,
                              hipStream_t stream)
{
    const void* x  = d_in[0];
    const void* W1 = d_in[1];
    const void* b1 = d_in[2];
    const void* W2 = d_in[3];
    const void* b2 = d_in[4];
    const int* ei = (const int*)d_in[5];
    const int E = in_sizes[5] / 2;

    // workspace carve-up (256B aligned)
    char* ws = (char*)d_ws;
    size_t off = 0;
    auto carve = [&](size_t bytes) -> void* {
        void* p = ws + off;
        off = (off + bytes + 255) & ~(size_t)255;
        return p;
    };
    float* h0    = (float*)carve((size_t)N_NODES * N_CLASSES * 4);
    float* zb0   = (float*)carve((size_t)N_NODES * N_CLASSES * 4);
    float* zb1   = (float*)carve((size_t)N_NODES * N_CLASSES * 4);
    int*   cnt   = (int*)  carve((size_t)N_NODES * 4);
    float* dinv  = (float*)carve((size_t)N_NODES * 4);
    int*   rptr  = (int*)  carve((size_t)(N_NODES + 1) * 4);
    int*   wpos  = (int*)  carve((size_t)N_NODES * 4);
    int*   srow  = (int*)  carve((size_t)E * 4);
    float* snorm = (float*)carve((size_t)E * 4);
    int*   flags = (int*)  carve(2 * sizeof(int));
    (void)ws_size; (void)n_in; (void)out_size;

    const int nodeBlocks = N_NODES / 4;          // 25000, N_NODES % 4 == 0
    const int nThreads1  = (N_NODES + 255) / 256;
    const int eBlocks    = (E + 255) / 256;

    // dtype detection
    zero_flags_kernel<<<1, 64, 0, stream>>>(flags);
    detect_float_kernel<<<128, 256, 0, stream>>>((const unsigned short*)W1, flags);
    detect_edge_kernel<<<8, 256, 0, stream>>>(ei, flags);

    // MLP (independent of graph preprocessing)
    mlp_kernel<<<nodeBlocks, 256, 0, stream>>>(x, W1, b1, W2, b2, flags, h0);

    // CSR-by-destination build
    zero_cnt_kernel<<<nThreads1, 256, 0, stream>>>(cnt);
    count_kernel<<<eBlocks, 256, 0, stream>>>(ei, flags, cnt, E);
    dinv_kernel<<<nThreads1, 256, 0, stream>>>(cnt, dinv);
    scan_kernel<<<1, 1024, 0, stream>>>(cnt, rptr, wpos, E);
    fill_kernel<<<eBlocks, 256, 0, stream>>>(ei, flags, dinv, wpos, srow, snorm, E);

    // K propagation steps (ping-pong)
    const float* zin = h0;
    float* zout = zb0;
    const float* zlast = h0;
    for (int it = 0; it < KITER; ++it) {
        prop_kernel<<<nodeBlocks, 256, 0, stream>>>(zin, h0, dinv, rptr, srow, snorm, zout);
        zlast = zout;
        zin = zout;
        zout = (zout == zb0) ? zb1 : zb0;
    }

    lsm_kernel<<<nodeBlocks, 256, 0, stream>>>(zlast, flags, d_out);
}

// Round 3
// 1857.615 us; speedup vs baseline: 2.1091x; 2.1091x over previous
//
#include <hip/hip_runtime.h>
#include <hip/hip_bf16.h>
#include <hip/hip_fp16.h>

#define N_NODES   100000
#define N_FEAT    512
#define HIDDEN    64
#define N_CLASSES 40
#define KITER     10
#define ALPHA     0.1f
#define ZP        64      // padded fp16 row pitch: 128 B -> one cacheline per gather

__device__ __forceinline__ float bf2f(unsigned short u) {
    union { unsigned int i; float f; } c;
    c.i = ((unsigned int)u) << 16;
    return c.f;
}

// ---------------- dtype detection (runs every call; data-driven, deterministic) ----
__global__ void zero_flags_kernel(int* __restrict__ flags) {
    if (threadIdx.x < 2) flags[threadIdx.x] = 0;
}

// flags[0] > 0  <=>  float tensors are fp32 (NaN/Inf bf16 bit-patterns in W1 raw halves)
__global__ void detect_float_kernel(const unsigned short* __restrict__ w1raw,
                                    int* __restrict__ flags) {
    int i = blockIdx.x * blockDim.x + threadIdx.x;
    if (i < 32768) {
        unsigned short u = w1raw[i];
        if ((u & 0x7F80u) == 0x7F80u) atomicAdd(&flags[0], 1);
    }
}

// flags[1] > 0  <=>  edges are int32 (some odd 32-bit word among first 2048 pairs nonzero)
__global__ void detect_edge_kernel(const int* __restrict__ ei, int* __restrict__ flags) {
    int i = blockIdx.x * blockDim.x + threadIdx.x;
    if (i < 2048) {
        if (ei[2 * i + 1] != 0) atomicAdd(&flags[1], 1);
    }
}

__device__ __forceinline__ int edge_row(const int* ei, int e, int E, int i64f) {
    return i64f ? ei[2 * e] : ei[e];
}
__device__ __forceinline__ int edge_col(const int* ei, int e, int E, int i64f) {
    return i64f ? ei[2 * E + 2 * e] : ei[E + e];
}

// ---------------- MLP: h0 = relu(x@W1+b1)@W2+b2 ----------------
// block = 4 waves, 16 nodes/block (4 nodes per wave) to amortize W1 L2 streaming.
__global__ __launch_bounds__(256) void mlp_kernel(
    const void* __restrict__ xp,
    const void* __restrict__ W1p,
    const void* __restrict__ b1p,
    const void* __restrict__ W2p,
    const void* __restrict__ b2p,
    const int* __restrict__ flags,
    float* __restrict__ h0,
    __half* __restrict__ zh0)
{
    __shared__ float xs[16][N_FEAT];   // 32 KB
    __shared__ float hs[16][HIDDEN];   // 4 KB
    const int t    = threadIdx.x;
    const int wave = t >> 6;
    const int lane = t & 63;
    const int base = blockIdx.x * 16;
    const int isf32 = flags[0] > 0;

    // ---- stage 16 x-rows into LDS (coalesced) ----
    if (isf32) {
        const float* xf = (const float*)xp;
        #pragma unroll
        for (int c = 0; c < 8; ++c) {
            int idx = c * 256 + t;              // [0,2048) float4 slots
            int row = idx >> 7;                 // 128 float4 per row
            int col = (idx & 127) * 4;
            float4 v = *(const float4*)(xf + (size_t)(base + row) * N_FEAT + col);
            xs[row][col + 0] = v.x; xs[row][col + 1] = v.y;
            xs[row][col + 2] = v.z; xs[row][col + 3] = v.w;
        }
    } else {
        const unsigned short* xb = (const unsigned short*)xp;
        #pragma unroll
        for (int c = 0; c < 4; ++c) {
            int idx = c * 256 + t;              // [0,1024) uint4 slots
            int row = idx >> 6;                 // 64 uint4 per row
            int col = (idx & 63) * 8;
            uint4 p = *(const uint4*)(xb + (size_t)(base + row) * N_FEAT + col);
            xs[row][col + 0] = bf2f((unsigned short)(p.x & 0xffff));
            xs[row][col + 1] = bf2f((unsigned short)(p.x >> 16));
            xs[row][col + 2] = bf2f((unsigned short)(p.y & 0xffff));
            xs[row][col + 3] = bf2f((unsigned short)(p.y >> 16));
            xs[row][col + 4] = bf2f((unsigned short)(p.z & 0xffff));
            xs[row][col + 5] = bf2f((unsigned short)(p.z >> 16));
            xs[row][col + 6] = bf2f((unsigned short)(p.w & 0xffff));
            xs[row][col + 7] = bf2f((unsigned short)(p.w >> 16));
        }
    }
    __syncthreads();

    // ---- layer 1: wave handles local rows r0..r0+3; lane = hidden unit ----
    const int r0 = wave * 4;
    float a0 = 0.f, a1 = 0.f, a2 = 0.f, a3 = 0.f;
    if (isf32) {
        const float* W1 = (const float*)W1p;
        #pragma unroll 8
        for (int k = 0; k < N_FEAT; ++k) {
            float wv = W1[k * HIDDEN + lane];
            a0 = fmaf(xs[r0 + 0][k], wv, a0);
            a1 = fmaf(xs[r0 + 1][k], wv, a1);
            a2 = fmaf(xs[r0 + 2][k], wv, a2);
            a3 = fmaf(xs[r0 + 3][k], wv, a3);
        }
    } else {
        const unsigned short* W1 = (const unsigned short*)W1p;
        #pragma unroll 8
        for (int k = 0; k < N_FEAT; ++k) {
            float wv = bf2f(W1[k * HIDDEN + lane]);
            a0 = fmaf(xs[r0 + 0][k], wv, a0);
            a1 = fmaf(xs[r0 + 1][k], wv, a1);
            a2 = fmaf(xs[r0 + 2][k], wv, a2);
            a3 = fmaf(xs[r0 + 3][k], wv, a3);
        }
    }
    float bb = isf32 ? ((const float*)b1p)[lane] : bf2f(((const unsigned short*)b1p)[lane]);
    hs[r0 + 0][lane] = fmaxf(a0 + bb, 0.0f);
    hs[r0 + 1][lane] = fmaxf(a1 + bb, 0.0f);
    hs[r0 + 2][lane] = fmaxf(a2 + bb, 0.0f);
    hs[r0 + 3][lane] = fmaxf(a3 + bb, 0.0f);
    __syncthreads();

    // ---- layer 2: wave handles its 4 nodes; lanes 0..39 = classes ----
    if (lane < N_CLASSES) {
        float b2v = isf32 ? ((const float*)b2p)[lane] : bf2f(((const unsigned short*)b2p)[lane]);
        #pragma unroll
        for (int i = 0; i < 4; ++i) {
            int node = base + r0 + i;
            float acc = b2v;
            if (isf32) {
                const float* W2 = (const float*)W2p;
                #pragma unroll
                for (int j = 0; j < HIDDEN; ++j)
                    acc = fmaf(hs[r0 + i][j], W2[j * N_CLASSES + lane], acc);
            } else {
                const unsigned short* W2 = (const unsigned short*)W2p;
                #pragma unroll
                for (int j = 0; j < HIDDEN; ++j)
                    acc = fmaf(hs[r0 + i][j], bf2f(W2[j * N_CLASSES + lane]), acc);
            }
            h0[(size_t)node * N_CLASSES + lane] = acc;
            zh0[(size_t)node * ZP + lane] = __float2half(acc);
        }
    }
}

// ---------------- graph preprocessing ----------------
__global__ void zero_cnt_kernel(int* __restrict__ cnt) {
    int i = blockIdx.x * blockDim.x + threadIdx.x;
    if (i < N_NODES) cnt[i] = 0;
}

__global__ void count_kernel(const int* __restrict__ ei, const int* __restrict__ flags,
                             int* __restrict__ cnt, int E) {
    int e = blockIdx.x * blockDim.x + threadIdx.x;
    int i64f = flags[1] == 0;
    if (e < E) atomicAdd(&cnt[edge_col(ei, e, E, i64f)], 1);
}

__global__ void dinv_kernel(const int* __restrict__ cnt, float* __restrict__ dinv) {
    int i = blockIdx.x * blockDim.x + threadIdx.x;
    if (i < N_NODES) dinv[i] = rsqrtf((float)cnt[i] + 1.0f);  // +1 self-loop
}

// shuffle-based exclusive scan: 4096 elems/tile, 4 barriers/tile, 25 tiles
__global__ __launch_bounds__(1024) void scan_kernel(
    const int* __restrict__ cnt, int* __restrict__ rptr, int* __restrict__ wpos, int E)
{
    __shared__ int wsum[16];
    __shared__ int carry_s, tiletot_s;
    const int t = threadIdx.x, wave = t >> 6, lane = t & 63;
    if (t == 0) carry_s = 0;
    __syncthreads();
    for (int base = 0; base < N_NODES; base += 4096) {
        int i0 = base + t * 4;
        int v0 = (i0 + 0 < N_NODES) ? cnt[i0 + 0] : 0;
        int v1 = (i0 + 1 < N_NODES) ? cnt[i0 + 1] : 0;
        int v2 = (i0 + 2 < N_NODES) ? cnt[i0 + 2] : 0;
        int v3 = (i0 + 3 < N_NODES) ? cnt[i0 + 3] : 0;
        int tl = v0 + v1 + v2 + v3;
        int sc = tl;
        #pragma unroll
        for (int off = 1; off < 64; off <<= 1) {
            int u = __shfl_up(sc, off, 64);
            if (lane >= off) sc += u;
        }
        if (lane == 63) wsum[wave] = sc;
        int wexcl = sc - tl;
        __syncthreads();
        if (wave == 0) {
            int wv = (lane < 16) ? wsum[lane] : 0;
            int ws = wv;
            #pragma unroll
            for (int off = 1; off < 16; off <<= 1) {
                int u = __shfl_up(ws, off, 64);
                if (lane >= off) ws += u;
            }
            if (lane < 16) wsum[lane] = ws - wv;   // exclusive
            if (lane == 15) tiletot_s = ws;        // inclusive tile total
        }
        __syncthreads();
        int P  = carry_s + wsum[wave] + wexcl;
        int e0 = P, e1 = P + v0, e2 = e1 + v1, e3 = e2 + v2;
        if (i0 + 0 < N_NODES) { rptr[i0 + 0] = e0; wpos[i0 + 0] = e0; }
        if (i0 + 1 < N_NODES) { rptr[i0 + 1] = e1; wpos[i0 + 1] = e1; }
        if (i0 + 2 < N_NODES) { rptr[i0 + 2] = e2; wpos[i0 + 2] = e2; }
        if (i0 + 3 < N_NODES) { rptr[i0 + 3] = e3; wpos[i0 + 3] = e3; }
        __syncthreads();
        if (t == 0) carry_s += tiletot_s;
        __syncthreads();
    }
    if (t == 0) rptr[N_NODES] = E;
}

__global__ void fill_kernel(const int* __restrict__ ei, const int* __restrict__ flags,
                            const float* __restrict__ dinv, int* __restrict__ wpos,
                            int2* __restrict__ srn, int E)
{
    int e = blockIdx.x * blockDim.x + threadIdx.x;
    int i64f = flags[1] == 0;
    if (e < E) {
        int r = edge_row(ei, e, E, i64f);
        int c = edge_col(ei, e, E, i64f);
        int pos = atomicAdd(&wpos[c], 1);
        srn[pos] = make_int2(r, __float_as_int(dinv[r] * dinv[c]));
    }
}

// ---------------- propagation: z_out = a*h0 + (1-a)*(A_hat @ z), z in fp16 ------
// pull mode via CSR-by-destination; one wave per node, lanes 0..39 = classes
__global__ __launch_bounds__(256) void prop_kernel(
    const __half* __restrict__ zh, const float* __restrict__ h0,
    const float* __restrict__ dinv, const int* __restrict__ rptr,
    const int2* __restrict__ srn, __half* __restrict__ zout)
{
    const int wave = threadIdx.x >> 6;
    const int lane = threadIdx.x & 63;
    const int node = blockIdx.x * 4 + wave;
    if (lane >= N_CLASSES) return;

    const int beg = rptr[node], end = rptr[node + 1];
    float a0 = 0.f, a1 = 0.f, a2 = 0.f, a3 = 0.f;
    int j = beg;
    for (; j + 4 <= end; j += 4) {
        int2 e0 = srn[j + 0];
        int2 e1 = srn[j + 1];
        int2 e2 = srn[j + 2];
        int2 e3 = srn[j + 3];
        float z0 = __half2float(zh[(size_t)e0.x * ZP + lane]);
        float z1 = __half2float(zh[(size_t)e1.x * ZP + lane]);
        float z2 = __half2float(zh[(size_t)e2.x * ZP + lane]);
        float z3 = __half2float(zh[(size_t)e3.x * ZP + lane]);
        a0 = fmaf(__int_as_float(e0.y), z0, a0);
        a1 = fmaf(__int_as_float(e1.y), z1, a1);
        a2 = fmaf(__int_as_float(e2.y), z2, a2);
        a3 = fmaf(__int_as_float(e3.y), z3, a3);
    }
    for (; j < end; ++j) {
        int2 e = srn[j];
        a0 = fmaf(__int_as_float(e.y), __half2float(zh[(size_t)e.x * ZP + lane]), a0);
    }
    float acc  = (a0 + a1) + (a2 + a3);
    float di   = dinv[node];
    float self = di * di * __half2float(zh[(size_t)node * ZP + lane]);
    float out  = ALPHA * h0[(size_t)node * N_CLASSES + lane]
               + (1.0f - ALPHA) * (acc + self);
    zout[(size_t)node * ZP + lane] = __float2half(out);
}

// ---------------- log_softmax + store (fp32 or bf16 per flags[0]) ----------------
__global__ __launch_bounds__(256) void lsm_kernel(
    const __half* __restrict__ zh, const int* __restrict__ flags, void* __restrict__ outp)
{
    const int wave = threadIdx.x >> 6;
    const int lane = threadIdx.x & 63;
    const int node = blockIdx.x * 4 + wave;
    const int isf32 = flags[0] > 0;

    float v = (lane < N_CLASSES) ? __half2float(zh[(size_t)node * ZP + lane]) : -1e30f;
    float m = v;
    #pragma unroll
    for (int o = 32; o; o >>= 1) m = fmaxf(m, __shfl_xor(m, o, 64));
    float e = (lane < N_CLASSES) ? expf(v - m) : 0.0f;
    float s = e;
    #pragma unroll
    for (int o = 32; o; o >>= 1) s += __shfl_xor(s, o, 64);
    float ls = logf(s);
    if (lane < N_CLASSES) {
        float r = v - m - ls;
        size_t idx = (size_t)node * N_CLASSES + lane;
        if (isf32) ((float*)outp)[idx] = r;
        else       ((__hip_bfloat16*)outp)[idx] = __float2bfloat16(r);
    }
}

extern "C" void kernel_launch(void* const* d_in, const int* in_sizes, int n_in,
                              void* d_out, int out_size, void* d_ws, size_t ws_size,
                              hipStream_t stream)
{
    const void* x  = d_in[0];
    const void* W1 = d_in[1];
    const void* b1 = d_in[2];
    const void* W2 = d_in[3];
    const void* b2 = d_in[4];
    const int* ei = (const int*)d_in[5];
    const int E = in_sizes[5] / 2;

    // workspace carve-up (256B aligned)
    char* ws = (char*)d_ws;
    size_t off = 0;
    auto carve = [&](size_t bytes) -> void* {
        void* p = ws + off;
        off = (off + bytes + 255) & ~(size_t)255;
        return p;
    };
    float*  h0    = (float*) carve((size_t)N_NODES * N_CLASSES * 4);
    __half* zhA   = (__half*)carve((size_t)N_NODES * ZP * 2);
    __half* zhB   = (__half*)carve((size_t)N_NODES * ZP * 2);
    int*    cnt   = (int*)   carve((size_t)N_NODES * 4);
    float*  dinv  = (float*) carve((size_t)N_NODES * 4);
    int*    rptr  = (int*)   carve((size_t)(N_NODES + 1) * 4);
    int*    wpos  = (int*)   carve((size_t)N_NODES * 4);
    int2*   srn   = (int2*)  carve((size_t)E * 8);
    int*    flags = (int*)   carve(2 * sizeof(int));
    (void)ws_size; (void)n_in; (void)out_size;

    const int nodeBlocks = N_NODES / 4;       // 25000
    const int mlpBlocks  = N_NODES / 16;      // 6250
    const int nThreads1  = (N_NODES + 255) / 256;
    const int eBlocks    = (E + 255) / 256;

    // dtype detection
    zero_flags_kernel<<<1, 64, 0, stream>>>(flags);
    detect_float_kernel<<<128, 256, 0, stream>>>((const unsigned short*)W1, flags);
    detect_edge_kernel<<<8, 256, 0, stream>>>(ei, flags);

    // MLP
    mlp_kernel<<<mlpBlocks, 256, 0, stream>>>(x, W1, b1, W2, b2, flags, h0, zhA);

    // CSR-by-destination build
    zero_cnt_kernel<<<nThreads1, 256, 0, stream>>>(cnt);
    count_kernel<<<eBlocks, 256, 0, stream>>>(ei, flags, cnt, E);
    dinv_kernel<<<nThreads1, 256, 0, stream>>>(cnt, dinv);
    scan_kernel<<<1, 1024, 0, stream>>>(cnt, rptr, wpos, E);
    fill_kernel<<<eBlocks, 256, 0, stream>>>(ei, flags, dinv, wpos, srn, E);

    // K propagation steps (ping-pong fp16)
    const __half* zin = zhA;
    __half* zout = zhB;
    const __half* zlast = zhA;
    for (int it = 0; it < KITER; ++it) {
        prop_kernel<<<nodeBlocks, 256, 0, stream>>>(zin, h0, dinv, rptr, srn, zout);
        zlast = zout;
        zin = zout;
        zout = (zout == zhB) ? zhA : zhB;
    }

    lsm_kernel<<<nodeBlocks, 256, 0, stream>>>(zlast, flags, d_out);
}

// Round 4
// 1488.372 us; speedup vs baseline: 2.6323x; 1.2481x over previous
//
#include <hip/hip_runtime.h>
#include <hip/hip_bf16.h>
#include <hip/hip_fp16.h>

#define N_NODES   100000
#define N_FEAT    512
#define HIDDEN    64
#define N_CLASSES 40
#define KITER     10
#define ALPHA     0.1f
#define ZP        64      // padded fp16 row pitch: 128 B -> one cacheline per gather

typedef __attribute__((ext_vector_type(8))) short bf16x8;
typedef __attribute__((ext_vector_type(4))) float f32x4;

__device__ __forceinline__ float bf2f(unsigned short u) {
    union { unsigned int i; float f; } c;
    c.i = ((unsigned int)u) << 16;
    return c.f;
}
__device__ __forceinline__ unsigned short f2bf(float f) {
    union { float f; unsigned int u; } c; c.f = f;
    unsigned int r = c.u + 0x7FFFu + ((c.u >> 16) & 1u);   // RNE
    return (unsigned short)(r >> 16);
}

// ---------------- dtype detection (runs every call; data-driven, deterministic) ----
__global__ void zero_flags_kernel(int* __restrict__ flags) {
    if (threadIdx.x < 2) flags[threadIdx.x] = 0;
}

// flags[0] > 0  <=>  float tensors are fp32 (NaN/Inf bf16 bit-patterns in W1 raw halves)
__global__ void detect_float_kernel(const unsigned short* __restrict__ w1raw,
                                    int* __restrict__ flags) {
    int i = blockIdx.x * blockDim.x + threadIdx.x;
    if (i < 32768) {
        unsigned short u = w1raw[i];
        if ((u & 0x7F80u) == 0x7F80u) atomicAdd(&flags[0], 1);
    }
}

// flags[1] > 0  <=>  edges are int32 (some odd 32-bit word among first 2048 pairs nonzero)
__global__ void detect_edge_kernel(const int* __restrict__ ei, int* __restrict__ flags) {
    int i = blockIdx.x * blockDim.x + threadIdx.x;
    if (i < 2048) {
        if (ei[2 * i + 1] != 0) atomicAdd(&flags[1], 1);
    }
}

__device__ __forceinline__ int edge_row(const int* ei, int e, int E, int i64f) {
    return i64f ? ei[2 * e] : ei[e];
}
__device__ __forceinline__ int edge_col(const int* ei, int e, int E, int i64f) {
    return i64f ? ei[2 * E + 2 * e] : ei[E + e];
}

// ---------------- pack W1 into MFMA B-fragment order (bf16) ----------------
// pb[((nt*16+kt)*64 + lane)*8 + j] = W1[(kt*32 + (lane>>4)*8 + j)*HIDDEN + nt*16 + (lane&15)]
__global__ void pack_w1_kernel(const void* __restrict__ W1p, const int* __restrict__ flags,
                               unsigned short* __restrict__ pb) {
    int idx = blockIdx.x * 256 + threadIdx.x;   // 32768 total
    int j    = idx & 7;
    int lane = (idx >> 3) & 63;
    int ktnt = idx >> 9;            // nt*16 + kt
    int kt = ktnt & 15, nt = ktnt >> 4;
    int k = kt * 32 + (lane >> 4) * 8 + j;
    int n = nt * 16 + (lane & 15);
    unsigned short v;
    if (flags[0] > 0) v = f2bf(((const float*)W1p)[k * HIDDEN + n]);
    else              v = ((const unsigned short*)W1p)[k * HIDDEN + n];
    pb[idx] = v;
}

// ---------------- MLP: h0 = relu(x@W1+b1)@W2+b2 ----------------
// layer 1 via MFMA 16x16x32 bf16: block = 4 waves = 4 N-tiles of 16, 16 nodes/block.
__global__ __launch_bounds__(256) void mlp_kernel(
    const void* __restrict__ xp,
    const unsigned short* __restrict__ pb,   // packed W1 B-frags
    const void* __restrict__ b1p,
    const void* __restrict__ W2p,
    const void* __restrict__ b2p,
    const int* __restrict__ flags,
    float* __restrict__ h0,
    __half* __restrict__ zh0)
{
    __shared__ float hs[16][HIDDEN];   // 4 KB
    const int t    = threadIdx.x;
    const int wave = t >> 6;           // = n-tile
    const int lane = t & 63;
    const int quad = lane >> 4;
    const int ml   = lane & 15;
    const int base = blockIdx.x * 16;
    const int isf32 = flags[0] > 0;

    const bf16x8* pbv = (const bf16x8*)pb;

    f32x4 acc = {0.f, 0.f, 0.f, 0.f};
    if (!isf32) {
        const unsigned short* xb = (const unsigned short*)xp;
        const unsigned short* xrow = xb + (size_t)(base + ml) * N_FEAT + quad * 8;
        #pragma unroll
        for (int kt = 0; kt < 16; ++kt) {
            bf16x8 a = *(const bf16x8*)(xrow + kt * 32);
            bf16x8 b = pbv[(wave * 16 + kt) * 64 + lane];
            acc = __builtin_amdgcn_mfma_f32_16x16x32_bf16(a, b, acc, 0, 0, 0);
        }
    } else {
        const float* xf = (const float*)xp + (size_t)(base + ml) * N_FEAT + quad * 8;
        #pragma unroll
        for (int kt = 0; kt < 16; ++kt) {
            float4 lo = *(const float4*)(xf + kt * 32);
            float4 hi = *(const float4*)(xf + kt * 32 + 4);
            bf16x8 a;
            a[0] = (short)f2bf(lo.x); a[1] = (short)f2bf(lo.y);
            a[2] = (short)f2bf(lo.z); a[3] = (short)f2bf(lo.w);
            a[4] = (short)f2bf(hi.x); a[5] = (short)f2bf(hi.y);
            a[6] = (short)f2bf(hi.z); a[7] = (short)f2bf(hi.w);
            bf16x8 b = pbv[(wave * 16 + kt) * 64 + lane];
            acc = __builtin_amdgcn_mfma_f32_16x16x32_bf16(a, b, acc, 0, 0, 0);
        }
    }

    // epilogue: bias + relu -> hs[m][n], m=quad*4+r, n=wave*16+ml
    float b1v = isf32 ? ((const float*)b1p)[wave * 16 + ml]
                      : bf2f(((const unsigned short*)b1p)[wave * 16 + ml]);
    #pragma unroll
    for (int r = 0; r < 4; ++r)
        hs[quad * 4 + r][wave * 16 + ml] = fmaxf(acc[r] + b1v, 0.0f);
    __syncthreads();

    // ---- layer 2: wave handles its 4 nodes; lanes 0..39 = classes ----
    const int r0 = wave * 4;
    if (lane < N_CLASSES) {
        float b2v = isf32 ? ((const float*)b2p)[lane] : bf2f(((const unsigned short*)b2p)[lane]);
        #pragma unroll
        for (int i = 0; i < 4; ++i) {
            int node = base + r0 + i;
            float acc2 = b2v;
            if (isf32) {
                const float* W2 = (const float*)W2p;
                #pragma unroll
                for (int j = 0; j < HIDDEN; ++j)
                    acc2 = fmaf(hs[r0 + i][j], W2[j * N_CLASSES + lane], acc2);
            } else {
                const unsigned short* W2 = (const unsigned short*)W2p;
                #pragma unroll
                for (int j = 0; j < HIDDEN; ++j)
                    acc2 = fmaf(hs[r0 + i][j], bf2f(W2[j * N_CLASSES + lane]), acc2);
            }
            h0[(size_t)node * N_CLASSES + lane] = acc2;
            zh0[(size_t)node * ZP + lane] = __float2half(acc2);
        }
    }
}

// ---------------- graph preprocessing ----------------
__global__ void zero_cnt_kernel(int* __restrict__ cnt) {
    int i = blockIdx.x * blockDim.x + threadIdx.x;
    if (i < N_NODES) cnt[i] = 0;
}

__global__ void count_kernel(const int* __restrict__ ei, const int* __restrict__ flags,
                             int* __restrict__ cnt, int E) {
    int e = blockIdx.x * blockDim.x + threadIdx.x;
    int i64f = flags[1] == 0;
    if (e < E) atomicAdd(&cnt[edge_col(ei, e, E, i64f)], 1);
}

__global__ void dinv_kernel(const int* __restrict__ cnt, float* __restrict__ dinv) {
    int i = blockIdx.x * blockDim.x + threadIdx.x;
    if (i < N_NODES) dinv[i] = rsqrtf((float)cnt[i] + 1.0f);  // +1 self-loop
}

// shuffle-based exclusive scan: 4096 elems/tile, 4 barriers/tile, 25 tiles
__global__ __launch_bounds__(1024) void scan_kernel(
    const int* __restrict__ cnt, int* __restrict__ rptr, int* __restrict__ wpos, int E)
{
    __shared__ int wsum[16];
    __shared__ int carry_s, tiletot_s;
    const int t = threadIdx.x, wave = t >> 6, lane = t & 63;
    if (t == 0) carry_s = 0;
    __syncthreads();
    for (int base = 0; base < N_NODES; base += 4096) {
        int i0 = base + t * 4;
        int v0 = (i0 + 0 < N_NODES) ? cnt[i0 + 0] : 0;
        int v1 = (i0 + 1 < N_NODES) ? cnt[i0 + 1] : 0;
        int v2 = (i0 + 2 < N_NODES) ? cnt[i0 + 2] : 0;
        int v3 = (i0 + 3 < N_NODES) ? cnt[i0 + 3] : 0;
        int tl = v0 + v1 + v2 + v3;
        int sc = tl;
        #pragma unroll
        for (int off = 1; off < 64; off <<= 1) {
            int u = __shfl_up(sc, off, 64);
            if (lane >= off) sc += u;
        }
        if (lane == 63) wsum[wave] = sc;
        int wexcl = sc - tl;
        __syncthreads();
        if (wave == 0) {
            int wv = (lane < 16) ? wsum[lane] : 0;
            int ws = wv;
            #pragma unroll
            for (int off = 1; off < 16; off <<= 1) {
                int u = __shfl_up(ws, off, 64);
                if (lane >= off) ws += u;
            }
            if (lane < 16) wsum[lane] = ws - wv;   // exclusive
            if (lane == 15) tiletot_s = ws;        // inclusive tile total
        }
        __syncthreads();
        int P  = carry_s + wsum[wave] + wexcl;
        int e0 = P, e1 = P + v0, e2 = e1 + v1, e3 = e2 + v2;
        if (i0 + 0 < N_NODES) { rptr[i0 + 0] = e0; wpos[i0 + 0] = e0; }
        if (i0 + 1 < N_NODES) { rptr[i0 + 1] = e1; wpos[i0 + 1] = e1; }
        if (i0 + 2 < N_NODES) { rptr[i0 + 2] = e2; wpos[i0 + 2] = e2; }
        if (i0 + 3 < N_NODES) { rptr[i0 + 3] = e3; wpos[i0 + 3] = e3; }
        __syncthreads();
        if (t == 0) carry_s += tiletot_s;
        __syncthreads();
    }
    if (t == 0) rptr[N_NODES] = E;
}

__global__ void fill_kernel(const int* __restrict__ ei, const int* __restrict__ flags,
                            const float* __restrict__ dinv, int* __restrict__ wpos,
                            int2* __restrict__ srn, int E)
{
    int e = blockIdx.x * blockDim.x + threadIdx.x;
    int i64f = flags[1] == 0;
    if (e < E) {
        int r = edge_row(ei, e, E, i64f);
        int c = edge_col(ei, e, E, i64f);
        int pos = atomicAdd(&wpos[c], 1);
        srn[pos] = make_int2(r, __float_as_int(dinv[r] * dinv[c]));
    }
}

// ---------------- propagation: z_out = a*h0 + (1-a)*(A_hat @ z), z in fp16 ------
// pull mode; one wave per node. Edge records fetched ONCE per 64 via a coalesced
// per-lane load, then broadcast via shuffles -> dependent chain = gather only.
__global__ __launch_bounds__(256) void prop_kernel(
    const __half* __restrict__ zh, const float* __restrict__ h0,
    const float* __restrict__ dinv, const int* __restrict__ rptr,
    const int2* __restrict__ srn, __half* __restrict__ zout)
{
    const int wave = threadIdx.x >> 6;
    const int lane = threadIdx.x & 63;
    const int node = blockIdx.x * 4 + wave;

    const int beg = rptr[node], end = rptr[node + 1];
    // issue long-latency scalar-ish loads early
    float h0v   = (lane < N_CLASSES) ? h0[(size_t)node * N_CLASSES + lane] : 0.0f;
    float selfz = __half2float(zh[(size_t)node * ZP + lane]);
    float di    = dinv[node];

    float a0 = 0.f, a1 = 0.f, a2 = 0.f, a3 = 0.f;
    float a4 = 0.f, a5 = 0.f, a6 = 0.f, a7 = 0.f;

    for (int cbeg = beg; cbeg < end; cbeg += 64) {
        const int cnt = min(64, end - cbeg);
        // one coalesced load: lane i holds edge record cbeg+i (all 64 lanes participate)
        int2 ew = (cbeg + lane < end) ? srn[cbeg + lane] : make_int2(0, 0);

        int i = 0;
        for (; i + 8 <= cnt; i += 8) {
            int   s0 = __shfl(ew.x, i + 0, 64), s1 = __shfl(ew.x, i + 1, 64);
            int   s2 = __shfl(ew.x, i + 2, 64), s3 = __shfl(ew.x, i + 3, 64);
            int   s4 = __shfl(ew.x, i + 4, 64), s5 = __shfl(ew.x, i + 5, 64);
            int   s6 = __shfl(ew.x, i + 6, 64), s7 = __shfl(ew.x, i + 7, 64);
            float n0 = __int_as_float(__shfl(ew.y, i + 0, 64));
            float n1 = __int_as_float(__shfl(ew.y, i + 1, 64));
            float n2 = __int_as_float(__shfl(ew.y, i + 2, 64));
            float n3 = __int_as_float(__shfl(ew.y, i + 3, 64));
            float n4 = __int_as_float(__shfl(ew.y, i + 4, 64));
            float n5 = __int_as_float(__shfl(ew.y, i + 5, 64));
            float n6 = __int_as_float(__shfl(ew.y, i + 6, 64));
            float n7 = __int_as_float(__shfl(ew.y, i + 7, 64));
            float z0 = __half2float(zh[(size_t)s0 * ZP + lane]);
            float z1 = __half2float(zh[(size_t)s1 * ZP + lane]);
            float z2 = __half2float(zh[(size_t)s2 * ZP + lane]);
            float z3 = __half2float(zh[(size_t)s3 * ZP + lane]);
            float z4 = __half2float(zh[(size_t)s4 * ZP + lane]);
            float z5 = __half2float(zh[(size_t)s5 * ZP + lane]);
            float z6 = __half2float(zh[(size_t)s6 * ZP + lane]);
            float z7 = __half2float(zh[(size_t)s7 * ZP + lane]);
            a0 = fmaf(n0, z0, a0); a1 = fmaf(n1, z1, a1);
            a2 = fmaf(n2, z2, a2); a3 = fmaf(n3, z3, a3);
            a4 = fmaf(n4, z4, a4); a5 = fmaf(n5, z5, a5);
            a6 = fmaf(n6, z6, a6); a7 = fmaf(n7, z7, a7);
        }
        for (; i < cnt; ++i) {
            int   s = __shfl(ew.x, i, 64);
            float n = __int_as_float(__shfl(ew.y, i, 64));
            a0 = fmaf(n, __half2float(zh[(size_t)s * ZP + lane]), a0);
        }
    }

    float acc = ((a0 + a1) + (a2 + a3)) + ((a4 + a5) + (a6 + a7));
    float out = ALPHA * h0v + (1.0f - ALPHA) * (acc + di * di * selfz);
    if (lane < N_CLASSES)
        zout[(size_t)node * ZP + lane] = __float2half(out);
}

// ---------------- log_softmax + store (fp32 or bf16 per flags[0]) ----------------
__global__ __launch_bounds__(256) void lsm_kernel(
    const __half* __restrict__ zh, const int* __restrict__ flags, void* __restrict__ outp)
{
    const int wave = threadIdx.x >> 6;
    const int lane = threadIdx.x & 63;
    const int node = blockIdx.x * 4 + wave;
    const int isf32 = flags[0] > 0;

    float v = (lane < N_CLASSES) ? __half2float(zh[(size_t)node * ZP + lane]) : -1e30f;
    float m = v;
    #pragma unroll
    for (int o = 32; o; o >>= 1) m = fmaxf(m, __shfl_xor(m, o, 64));
    float e = (lane < N_CLASSES) ? expf(v - m) : 0.0f;
    float s = e;
    #pragma unroll
    for (int o = 32; o; o >>= 1) s += __shfl_xor(s, o, 64);
    float ls = logf(s);
    if (lane < N_CLASSES) {
        float r = v - m - ls;
        size_t idx = (size_t)node * N_CLASSES + lane;
        if (isf32) ((float*)outp)[idx] = r;
        else       ((__hip_bfloat16*)outp)[idx] = __float2bfloat16(r);
    }
}

extern "C" void kernel_launch(void* const* d_in, const int* in_sizes, int n_in,
                              void* d_out, int out_size, void* d_ws, size_t ws_size,
                              hipStream_t stream)
{
    const void* x  = d_in[0];
    const void* W1 = d_in[1];
    const void* b1 = d_in[2];
    const void* W2 = d_in[3];
    const void* b2 = d_in[4];
    const int* ei = (const int*)d_in[5];
    const int E = in_sizes[5] / 2;

    // workspace carve-up (256B aligned)
    char* ws = (char*)d_ws;
    size_t off = 0;
    auto carve = [&](size_t bytes) -> void* {
        void* p = ws + off;
        off = (off + bytes + 255) & ~(size_t)255;
        return p;
    };
    float*  h0    = (float*) carve((size_t)N_NODES * N_CLASSES * 4);
    __half* zhA   = (__half*)carve((size_t)N_NODES * ZP * 2);
    __half* zhB   = (__half*)carve((size_t)N_NODES * ZP * 2);
    int*    cnt   = (int*)   carve((size_t)N_NODES * 4);
    float*  dinv  = (float*) carve((size_t)N_NODES * 4);
    int*    rptr  = (int*)   carve((size_t)(N_NODES + 1) * 4);
    int*    wpos  = (int*)   carve((size_t)N_NODES * 4);
    int2*   srn   = (int2*)  carve((size_t)E * 8);
    unsigned short* pb = (unsigned short*)carve(32768 * 2);
    int*    flags = (int*)   carve(2 * sizeof(int));
    (void)ws_size; (void)n_in; (void)out_size;

    const int nodeBlocks = N_NODES / 4;       // 25000
    const int mlpBlocks  = N_NODES / 16;      // 6250
    const int nThreads1  = (N_NODES + 255) / 256;
    const int eBlocks    = (E + 255) / 256;

    // dtype detection + W1 pack
    zero_flags_kernel<<<1, 64, 0, stream>>>(flags);
    detect_float_kernel<<<128, 256, 0, stream>>>((const unsigned short*)W1, flags);
    detect_edge_kernel<<<8, 256, 0, stream>>>(ei, flags);
    pack_w1_kernel<<<128, 256, 0, stream>>>(W1, flags, pb);

    // MLP (MFMA layer 1)
    mlp_kernel<<<mlpBlocks, 256, 0, stream>>>(x, pb, b1, W2, b2, flags, h0, zhA);

    // CSR-by-destination build
    zero_cnt_kernel<<<nThreads1, 256, 0, stream>>>(cnt);
    count_kernel<<<eBlocks, 256, 0, stream>>>(ei, flags, cnt, E);
    dinv_kernel<<<nThreads1, 256, 0, stream>>>(cnt, dinv);
    scan_kernel<<<1, 1024, 0, stream>>>(cnt, rptr, wpos, E);
    fill_kernel<<<eBlocks, 256, 0, stream>>>(ei, flags, dinv, wpos, srn, E);

    // K propagation steps (ping-pong fp16)
    const __half* zin = zhA;
    __half* zout = zhB;
    const __half* zlast = zhA;
    for (int it = 0; it < KITER; ++it) {
        prop_kernel<<<nodeBlocks, 256, 0, stream>>>(zin, h0, dinv, rptr, srn, zout);
        zlast = zout;
        zin = zout;
        zout = (zout == zhB) ? zhA : zhB;
    }

    lsm_kernel<<<nodeBlocks, 256, 0, stream>>>(zlast, flags, d_out);
}

// Round 5
// 1269.746 us; speedup vs baseline: 3.0856x; 1.1722x over previous
//
#include <hip/hip_runtime.h>
#include <hip/hip_bf16.h>
#include <hip/hip_fp16.h>

#define N_NODES   100000
#define N_FEAT    512
#define HIDDEN    64
#define N_CLASSES 40
#define KITER     10
#define ALPHA     0.1f
#define ZP        64      // padded fp16 row pitch: 128 B -> one cacheline per row
#define HPITCH    72      // LDS h pitch in halves (144 B) to break bank conflicts

typedef __attribute__((ext_vector_type(8))) short bf16x8;
typedef __attribute__((ext_vector_type(4))) float f32x4;

__device__ __forceinline__ float bf2f(unsigned short u) {
    union { unsigned int i; float f; } c;
    c.i = ((unsigned int)u) << 16;
    return c.f;
}
__device__ __forceinline__ unsigned short f2bf(float f) {
    union { float f; unsigned int u; } c; c.f = f;
    unsigned int r = c.u + 0x7FFFu + ((c.u >> 16) & 1u);   // RNE
    return (unsigned short)(r >> 16);
}

// ---------------- dtype detection (runs every call; data-driven, deterministic) ----
__global__ void zero_flags_kernel(int* __restrict__ flags) {
    if (threadIdx.x < 2) flags[threadIdx.x] = 0;
}

__global__ void detect_float_kernel(const unsigned short* __restrict__ w1raw,
                                    int* __restrict__ flags) {
    int i = blockIdx.x * blockDim.x + threadIdx.x;
    if (i < 32768) {
        unsigned short u = w1raw[i];
        if ((u & 0x7F80u) == 0x7F80u) atomicAdd(&flags[0], 1);
    }
}

__global__ void detect_edge_kernel(const int* __restrict__ ei, int* __restrict__ flags) {
    int i = blockIdx.x * blockDim.x + threadIdx.x;
    if (i < 2048) {
        if (ei[2 * i + 1] != 0) atomicAdd(&flags[1], 1);
    }
}

__device__ __forceinline__ int edge_row(const int* ei, int e, int E, int i64f) {
    return i64f ? ei[2 * e] : ei[e];
}
__device__ __forceinline__ int edge_col(const int* ei, int e, int E, int i64f) {
    return i64f ? ei[2 * E + 2 * e] : ei[E + e];
}

// ---------------- pack W1 into MFMA B-fragment order (bf16) ----------------
__global__ void pack_w1_kernel(const void* __restrict__ W1p, const int* __restrict__ flags,
                               unsigned short* __restrict__ pb) {
    int idx = blockIdx.x * 256 + threadIdx.x;   // 32768 total
    int j    = idx & 7;
    int lane = (idx >> 3) & 63;
    int ktnt = idx >> 9;            // nt*16 + kt
    int kt = ktnt & 15, nt = ktnt >> 4;
    int k = kt * 32 + (lane >> 4) * 8 + j;
    int n = nt * 16 + (lane & 15);
    unsigned short v;
    if (flags[0] > 0) v = f2bf(((const float*)W1p)[k * HIDDEN + n]);
    else              v = ((const unsigned short*)W1p)[k * HIDDEN + n];
    pb[idx] = v;
}

// ---------------- pack W2 (64x40) into B-frag order, N padded to 48 -------------
// pb2[((nt*2+kt)*64 + lane)*8 + j] = W2[kt*32 + (lane>>4)*8 + j][nt*16 + (lane&15)]
__global__ void pack_w2_kernel(const void* __restrict__ W2p, const int* __restrict__ flags,
                               unsigned short* __restrict__ pb2) {
    int idx = blockIdx.x * 256 + threadIdx.x;   // 3072 total
    if (idx >= 3072) return;
    int j    = idx & 7;
    int lane = (idx >> 3) & 63;
    int ktnt = idx >> 9;            // nt*2 + kt
    int kt = ktnt & 1, nt = ktnt >> 1;
    int k = kt * 32 + (lane >> 4) * 8 + j;
    int n = nt * 16 + (lane & 15);
    unsigned short v = 0;
    if (n < N_CLASSES) {
        if (flags[0] > 0) v = f2bf(((const float*)W2p)[k * N_CLASSES + n]);
        else              v = ((const unsigned short*)W2p)[k * N_CLASSES + n];
    }
    pb2[idx] = v;
}

// ---------------- MLP: h0 = relu(x@W1+b1)@W2+b2, both layers MFMA --------------
__global__ __launch_bounds__(256) void mlp_kernel(
    const void* __restrict__ xp,
    const unsigned short* __restrict__ pb,    // packed W1 B-frags
    const unsigned short* __restrict__ pb2,   // packed W2 B-frags
    const void* __restrict__ b1p,
    const void* __restrict__ b2p,
    const int* __restrict__ flags,
    float* __restrict__ h0,
    __half* __restrict__ zh0)
{
    __shared__ unsigned short hsb[16 * HPITCH];   // h in bf16, 2.25 KB
    const int t    = threadIdx.x;
    const int wave = t >> 6;           // layer1: n-tile; layer2: n-tile (0..2)
    const int lane = t & 63;
    const int quad = lane >> 4;
    const int ml   = lane & 15;
    const int base = blockIdx.x * 16;
    const int isf32 = flags[0] > 0;

    const bf16x8* pbv = (const bf16x8*)pb;

    // ---- layer 1: MFMA 16x16x32, m=16 nodes, n-tile=wave ----
    f32x4 acc = {0.f, 0.f, 0.f, 0.f};
    if (!isf32) {
        const unsigned short* xrow = (const unsigned short*)xp
                                   + (size_t)(base + ml) * N_FEAT + quad * 8;
        #pragma unroll
        for (int kt = 0; kt < 16; ++kt) {
            bf16x8 a = *(const bf16x8*)(xrow + kt * 32);
            bf16x8 b = pbv[(wave * 16 + kt) * 64 + lane];
            acc = __builtin_amdgcn_mfma_f32_16x16x32_bf16(a, b, acc, 0, 0, 0);
        }
    } else {
        const float* xf = (const float*)xp + (size_t)(base + ml) * N_FEAT + quad * 8;
        #pragma unroll
        for (int kt = 0; kt < 16; ++kt) {
            float4 lo = *(const float4*)(xf + kt * 32);
            float4 hi = *(const float4*)(xf + kt * 32 + 4);
            bf16x8 a;
            a[0] = (short)f2bf(lo.x); a[1] = (short)f2bf(lo.y);
            a[2] = (short)f2bf(lo.z); a[3] = (short)f2bf(lo.w);
            a[4] = (short)f2bf(hi.x); a[5] = (short)f2bf(hi.y);
            a[6] = (short)f2bf(hi.z); a[7] = (short)f2bf(hi.w);
            bf16x8 b = pbv[(wave * 16 + kt) * 64 + lane];
            acc = __builtin_amdgcn_mfma_f32_16x16x32_bf16(a, b, acc, 0, 0, 0);
        }
    }

    // bias + relu -> LDS as bf16: h[node=quad*4+r][hid=wave*16+ml]
    float b1v = isf32 ? ((const float*)b1p)[wave * 16 + ml]
                      : bf2f(((const unsigned short*)b1p)[wave * 16 + ml]);
    #pragma unroll
    for (int r = 0; r < 4; ++r)
        hsb[(quad * 4 + r) * HPITCH + wave * 16 + ml] = f2bf(fmaxf(acc[r] + b1v, 0.0f));
    __syncthreads();

    // ---- layer 2: MFMA, m=16 nodes, K=64 (2 k-tiles), n padded to 48 (3 tiles) ----
    if (wave < 3) {
        const bf16x8* pb2v = (const bf16x8*)pb2;
        f32x4 acc2 = {0.f, 0.f, 0.f, 0.f};
        #pragma unroll
        for (int kt = 0; kt < 2; ++kt) {
            bf16x8 a = *(const bf16x8*)(hsb + ml * HPITCH + kt * 32 + quad * 8);
            bf16x8 b = pb2v[(wave * 2 + kt) * 64 + lane];
            acc2 = __builtin_amdgcn_mfma_f32_16x16x32_bf16(a, b, acc2, 0, 0, 0);
        }
        int n = wave * 16 + ml;
        if (n < N_CLASSES) {
            float b2v = isf32 ? ((const float*)b2p)[n] : bf2f(((const unsigned short*)b2p)[n]);
            #pragma unroll
            for (int r = 0; r < 4; ++r) {
                int node = base + quad * 4 + r;
                float v = acc2[r] + b2v;
                h0[(size_t)node * N_CLASSES + n] = v;
                zh0[(size_t)node * ZP + n] = __float2half(v);
            }
        }
    }
}

// ---------------- graph preprocessing ----------------
__global__ void zero_cnt_kernel(int* __restrict__ cnt) {
    int i = blockIdx.x * blockDim.x + threadIdx.x;
    if (i < N_NODES) cnt[i] = 0;
}

__global__ void count_kernel(const int* __restrict__ ei, const int* __restrict__ flags,
                             int* __restrict__ cnt, int E) {
    int e = blockIdx.x * blockDim.x + threadIdx.x;
    int i64f = flags[1] == 0;
    if (e < E) atomicAdd(&cnt[edge_col(ei, e, E, i64f)], 1);
}

__global__ void dinv_kernel(const int* __restrict__ cnt, float* __restrict__ dinv) {
    int i = blockIdx.x * blockDim.x + threadIdx.x;
    if (i < N_NODES) dinv[i] = rsqrtf((float)cnt[i] + 1.0f);  // +1 self-loop
}

// shuffle-based exclusive scan: 4096 elems/tile, 4 barriers/tile, 25 tiles
__global__ __launch_bounds__(1024) void scan_kernel(
    const int* __restrict__ cnt, int* __restrict__ rptr, int* __restrict__ wpos, int E)
{
    __shared__ int wsum[16];
    __shared__ int carry_s, tiletot_s;
    const int t = threadIdx.x, wave = t >> 6, lane = t & 63;
    if (t == 0) carry_s = 0;
    __syncthreads();
    for (int base = 0; base < N_NODES; base += 4096) {
        int i0 = base + t * 4;
        int v0 = (i0 + 0 < N_NODES) ? cnt[i0 + 0] : 0;
        int v1 = (i0 + 1 < N_NODES) ? cnt[i0 + 1] : 0;
        int v2 = (i0 + 2 < N_NODES) ? cnt[i0 + 2] : 0;
        int v3 = (i0 + 3 < N_NODES) ? cnt[i0 + 3] : 0;
        int tl = v0 + v1 + v2 + v3;
        int sc = tl;
        #pragma unroll
        for (int off = 1; off < 64; off <<= 1) {
            int u = __shfl_up(sc, off, 64);
            if (lane >= off) sc += u;
        }
        if (lane == 63) wsum[wave] = sc;
        int wexcl = sc - tl;
        __syncthreads();
        if (wave == 0) {
            int wv = (lane < 16) ? wsum[lane] : 0;
            int ws = wv;
            #pragma unroll
            for (int off = 1; off < 16; off <<= 1) {
                int u = __shfl_up(ws, off, 64);
                if (lane >= off) ws += u;
            }
            if (lane < 16) wsum[lane] = ws - wv;   // exclusive
            if (lane == 15) tiletot_s = ws;        // inclusive tile total
        }
        __syncthreads();
        int P  = carry_s + wsum[wave] + wexcl;
        int e0 = P, e1 = P + v0, e2 = e1 + v1, e3 = e2 + v2;
        if (i0 + 0 < N_NODES) { rptr[i0 + 0] = e0; wpos[i0 + 0] = e0; }
        if (i0 + 1 < N_NODES) { rptr[i0 + 1] = e1; wpos[i0 + 1] = e1; }
        if (i0 + 2 < N_NODES) { rptr[i0 + 2] = e2; wpos[i0 + 2] = e2; }
        if (i0 + 3 < N_NODES) { rptr[i0 + 3] = e3; wpos[i0 + 3] = e3; }
        __syncthreads();
        if (t == 0) carry_s += tiletot_s;
        __syncthreads();
    }
    if (t == 0) rptr[N_NODES] = E;
}

__global__ void fill_kernel(const int* __restrict__ ei, const int* __restrict__ flags,
                            const float* __restrict__ dinv, int* __restrict__ wpos,
                            int2* __restrict__ srn, int E)
{
    int e = blockIdx.x * blockDim.x + threadIdx.x;
    int i64f = flags[1] == 0;
    if (e < E) {
        int r = edge_row(ei, e, E, i64f);
        int c = edge_col(ei, e, E, i64f);
        int pos = atomicAdd(&wpos[c], 1);
        srn[pos] = make_int2(r, __float_as_int(dinv[r] * dinv[c]));
    }
}

// ---------------- propagation: z_out = a*h0 + (1-a)*(A_hat @ z), z in fp16 ------
// 4 nodes per wave: 16 lanes per node, each lane holds 4 classes (uint2 = 4 halves).
// One gather instruction serves 4 edges (one per node group).
__global__ __launch_bounds__(256) void prop_kernel(
    const __half* __restrict__ zh, const float* __restrict__ h0,
    const float* __restrict__ dinv, const int* __restrict__ rptr,
    const int2* __restrict__ srn, __half* __restrict__ zout, int E)
{
    const int wave = threadIdx.x >> 6;
    const int lane = threadIdx.x & 63;
    const int g    = lane >> 4;        // node subgroup 0..3
    const int l    = lane & 15;        // lane within group
    const int node = blockIdx.x * 16 + wave * 4 + g;
    const int c0   = l * 4;            // first class handled by this lane

    const int beg = rptr[node];
    const int end = rptr[node + 1];
    int nch = (end - beg + 15) >> 4;
    int m1    = max(nch, __shfl_xor(nch, 16, 64));
    int maxch = max(m1,  __shfl_xor(m1, 32, 64));

    // issue long-latency per-node loads early
    float di = dinv[node];
    uint2 zzs = *(const uint2*)(zh + ((size_t)node << 6) + c0);
    float h00 = 0.f, h01 = 0.f, h02 = 0.f, h03 = 0.f;
    if (c0 < N_CLASSES) {
        const float* hp = h0 + (size_t)node * N_CLASSES + c0;
        h00 = hp[0]; h01 = hp[1]; h02 = hp[2]; h03 = hp[3];
    }

    float a0 = 0.f, a1 = 0.f, a2 = 0.f, a3 = 0.f;
    float b0 = 0.f, b1 = 0.f, b2 = 0.f, b3 = 0.f;

    for (int ch = 0; ch < maxch; ++ch) {
        int idx  = beg + ch * 16 + l;
        bool v   = idx < end;
        int cidx = v ? idx : beg;
        cidx = min(cidx, E - 1);
        int2 ew  = srn[cidx];
        int   sw = ew.x;
        float nw = v ? __int_as_float(ew.y) : 0.0f;

        #pragma unroll
        for (int i = 0; i < 16; i += 2) {
            int   s0 = __shfl(sw, (g << 4) + i,     64);
            float n0 = __shfl(nw, (g << 4) + i,     64);
            int   s1 = __shfl(sw, (g << 4) + i + 1, 64);
            float n1 = __shfl(nw, (g << 4) + i + 1, 64);
            uint2 z0 = *(const uint2*)(zh + ((size_t)s0 << 6) + c0);
            uint2 z1 = *(const uint2*)(zh + ((size_t)s1 << 6) + c0);
            const __half2* p0 = (const __half2*)&z0;
            const __half2* p1 = (const __half2*)&z1;
            float2 f00 = __half22float2(p0[0]);
            float2 f01 = __half22float2(p0[1]);
            float2 f10 = __half22float2(p1[0]);
            float2 f11 = __half22float2(p1[1]);
            a0 = fmaf(n0, f00.x, a0); a1 = fmaf(n0, f00.y, a1);
            a2 = fmaf(n0, f01.x, a2); a3 = fmaf(n0, f01.y, a3);
            b0 = fmaf(n1, f10.x, b0); b1 = fmaf(n1, f10.y, b1);
            b2 = fmaf(n1, f11.x, b2); b3 = fmaf(n1, f11.y, b3);
        }
    }

    if (c0 < N_CLASSES) {
        const __half2* ps = (const __half2*)&zzs;
        float2 s01 = __half22float2(ps[0]);
        float2 s23 = __half22float2(ps[1]);
        float dd = di * di;
        float o0 = ALPHA * h00 + (1.0f - ALPHA) * (a0 + b0 + dd * s01.x);
        float o1 = ALPHA * h01 + (1.0f - ALPHA) * (a1 + b1 + dd * s01.y);
        float o2 = ALPHA * h02 + (1.0f - ALPHA) * (a2 + b2 + dd * s23.x);
        float o3 = ALPHA * h03 + (1.0f - ALPHA) * (a3 + b3 + dd * s23.y);
        __half2 q01 = __floats2half2_rn(o0, o1);
        __half2 q23 = __floats2half2_rn(o2, o3);
        uint2 st;
        st.x = *(unsigned int*)&q01;
        st.y = *(unsigned int*)&q23;
        *(uint2*)(zout + ((size_t)node << 6) + c0) = st;
    }
}

// ---------------- log_softmax + store (fp32 or bf16 per flags[0]) ----------------
__global__ __launch_bounds__(256) void lsm_kernel(
    const __half* __restrict__ zh, const int* __restrict__ flags, void* __restrict__ outp)
{
    const int wave = threadIdx.x >> 6;
    const int lane = threadIdx.x & 63;
    const int node = blockIdx.x * 4 + wave;
    const int isf32 = flags[0] > 0;

    float v = (lane < N_CLASSES) ? __half2float(zh[(size_t)node * ZP + lane]) : -1e30f;
    float m = v;
    #pragma unroll
    for (int o = 32; o; o >>= 1) m = fmaxf(m, __shfl_xor(m, o, 64));
    float e = (lane < N_CLASSES) ? expf(v - m) : 0.0f;
    float s = e;
    #pragma unroll
    for (int o = 32; o; o >>= 1) s += __shfl_xor(s, o, 64);
    float ls = logf(s);
    if (lane < N_CLASSES) {
        float r = v - m - ls;
        size_t idx = (size_t)node * N_CLASSES + lane;
        if (isf32) ((float*)outp)[idx] = r;
        else       ((__hip_bfloat16*)outp)[idx] = __float2bfloat16(r);
    }
}

extern "C" void kernel_launch(void* const* d_in, const int* in_sizes, int n_in,
                              void* d_out, int out_size, void* d_ws, size_t ws_size,
                              hipStream_t stream)
{
    const void* x  = d_in[0];
    const void* W1 = d_in[1];
    const void* b1 = d_in[2];
    const void* W2 = d_in[3];
    const void* b2 = d_in[4];
    const int* ei = (const int*)d_in[5];
    const int E = in_sizes[5] / 2;

    // workspace carve-up (256B aligned)
    char* ws = (char*)d_ws;
    size_t off = 0;
    auto carve = [&](size_t bytes) -> void* {
        void* p = ws + off;
        off = (off + bytes + 255) & ~(size_t)255;
        return p;
    };
    float*  h0    = (float*) carve((size_t)N_NODES * N_CLASSES * 4);
    __half* zhA   = (__half*)carve((size_t)N_NODES * ZP * 2);
    __half* zhB   = (__half*)carve((size_t)N_NODES * ZP * 2);
    int*    cnt   = (int*)   carve((size_t)N_NODES * 4);
    float*  dinv  = (float*) carve((size_t)N_NODES * 4);
    int*    rptr  = (int*)   carve((size_t)(N_NODES + 1) * 4);
    int*    wpos  = (int*)   carve((size_t)N_NODES * 4);
    int2*   srn   = (int2*)  carve((size_t)E * 8);
    unsigned short* pb  = (unsigned short*)carve(32768 * 2);
    unsigned short* pb2 = (unsigned short*)carve(3072 * 2);
    int*    flags = (int*)   carve(2 * sizeof(int));
    (void)ws_size; (void)n_in; (void)out_size;

    const int nodeBlocks = N_NODES / 4;       // 25000
    const int mlpBlocks  = N_NODES / 16;      // 6250
    const int propBlocks = N_NODES / 16;      // 6250 (16 nodes per block)
    const int nThreads1  = (N_NODES + 255) / 256;
    const int eBlocks    = (E + 255) / 256;

    // dtype detection + weight packing
    zero_flags_kernel<<<1, 64, 0, stream>>>(flags);
    detect_float_kernel<<<128, 256, 0, stream>>>((const unsigned short*)W1, flags);
    detect_edge_kernel<<<8, 256, 0, stream>>>(ei, flags);
    pack_w1_kernel<<<128, 256, 0, stream>>>(W1, flags, pb);
    pack_w2_kernel<<<12, 256, 0, stream>>>(W2, flags, pb2);

    // MLP (both layers MFMA)
    mlp_kernel<<<mlpBlocks, 256, 0, stream>>>(x, pb, pb2, b1, b2, flags, h0, zhA);

    // CSR-by-destination build
    zero_cnt_kernel<<<nThreads1, 256, 0, stream>>>(cnt);
    count_kernel<<<eBlocks, 256, 0, stream>>>(ei, flags, cnt, E);
    dinv_kernel<<<nThreads1, 256, 0, stream>>>(cnt, dinv);
    scan_kernel<<<1, 1024, 0, stream>>>(cnt, rptr, wpos, E);
    fill_kernel<<<eBlocks, 256, 0, stream>>>(ei, flags, dinv, wpos, srn, E);

    // K propagation steps (ping-pong fp16)
    const __half* zin = zhA;
    __half* zout = zhB;
    const __half* zlast = zhA;
    for (int it = 0; it < KITER; ++it) {
        prop_kernel<<<propBlocks, 256, 0, stream>>>(zin, h0, dinv, rptr, srn, zout, E);
        zlast = zout;
        zin = zout;
        zout = (zout == zhB) ? zhA : zhB;
    }

    lsm_kernel<<<nodeBlocks, 256, 0, stream>>>(zlast, flags, d_out);
}